// Round 1
// baseline (479.335 us; speedup 1.0000x reference)
//
#include <hip/hip_runtime.h>
#include <stdint.h>

#define Bb 8
#define Ss 2048
#define Hh 16
#define Aa 128
#define Dd 128
#define NGATE 384
#define KDIM 256
#define NCH 16
#define CLEN 128
#define ROWS (Bb*Ss)          // 16384 (b,s) rows
#define ROWSTR (Hh*Aa)        // 2048 elements per (b,s) row

typedef float f32x4 __attribute__((ext_vector_type(4)));
typedef __bf16 bf16x8 __attribute__((ext_vector_type(8)));
typedef unsigned short u16x8 __attribute__((ext_vector_type(8)));

static __device__ __forceinline__ unsigned short f2bf(float f){
  unsigned int u = __builtin_bit_cast(unsigned int, f);
  u += 0x7FFFu + ((u >> 16) & 1u);
  return (unsigned short)(u >> 16);
}
static __device__ __forceinline__ float bf2f(unsigned short s){
  unsigned int u = ((unsigned int)s) << 16;
  return __builtin_bit_cast(float, u);
}
static __device__ __forceinline__ float sigf(float x){ return 1.0f/(1.0f + __expf(-x)); }

// ---- weight conversion: fp32 -> bf16, transposed to [h][n][k], gates-permuted for w_hid ----
__global__ void k_conv_whid(const float* __restrict__ w, unsigned short* __restrict__ wt){
  int idx = blockIdx.x*256 + threadIdx.x;
  const int total = Hh*KDIM*NGATE;
  for (; idx < total; idx += gridDim.x*256){
    int o = idx % NGATE; int k = (idx/NGATE) % KDIM; int h = idx/(NGATE*KDIM);
    int g = o >> 7, d = o & 127;                     // gate, channel
    int np = (d >> 4)*48 + g*16 + (d & 15);          // interleave (ig,fg,hd) per 16-col block
    wt[((size_t)h*NGATE + np)*KDIM + k] = f2bf(w[idx]);
  }
}
__global__ void k_conv_wog(const float* __restrict__ w, unsigned short* __restrict__ wt){
  int idx = blockIdx.x*256 + threadIdx.x;
  const int total = Hh*KDIM*Dd;
  for (; idx < total; idx += gridDim.x*256){
    int o = idx % Dd; int k = (idx/Dd) % KDIM; int h = idx/(Dd*KDIM);
    wt[((size_t)h*Dd + o)*KDIM + k] = f2bf(w[idx]);
  }
}

// ---- cumsum pass A: chunk totals ----
__global__ void k_cumsum_a(const float* __restrict__ x, float* __restrict__ totals){
  int c = blockIdx.x;                       // ((b*Hh+h)*NCH + k)
  int k = c % NCH; int hb = c / NCH;
  int b = hb / Hh, h = hb % Hh;
  int a = threadIdx.x;
  const float* p = x + ((size_t)(b*Ss + k*CLEN)*Hh + h)*Aa + a;
  float run = 0.f;
  #pragma unroll 4
  for (int i = 0; i < CLEN; ++i) run += p[(size_t)i*ROWSTR];
  totals[(size_t)c*Aa + a] = run;
}

// ---- cumsum pass C: carry-in + write bf16 csum ----
__global__ void k_cumsum_c(const float* __restrict__ x, const float* __restrict__ totals,
                           unsigned short* __restrict__ csum){
  int c = blockIdx.x;
  int k = c % NCH; int hb = c / NCH;
  int b = hb / Hh, h = hb % Hh;
  int a = threadIdx.x;
  const float* tp = totals + (size_t)hb*NCH*Aa + a;
  float run = 0.f;
  for (int j = 0; j < k; ++j) run += tp[(size_t)j*Aa];
  const float* p = x + ((size_t)(b*Ss + k*CLEN)*Hh + h)*Aa + a;
  unsigned short* q = csum + ((size_t)(b*Ss + k*CLEN)*Hh + h)*Aa + a;
  #pragma unroll 2
  for (int i = 0; i < CLEN; ++i){
    run += p[(size_t)i*ROWSTR];
    q[(size_t)i*ROWSTR] = f2bf(run);
  }
}

// ---- LN stats per (b,s) over H*A = 2048 values ----
__global__ void k_stats(const unsigned short* __restrict__ csum, float2* __restrict__ mr){
  int r = blockIdx.x;
  int t = threadIdx.x;                      // 256
  const u16x8 v = *(const u16x8*)(csum + (size_t)r*ROWSTR + t*8);
  float s = 0.f, q = 0.f;
  #pragma unroll
  for (int i = 0; i < 8; ++i){ float f = bf2f(v[i]); s += f; q += f*f; }
  #pragma unroll
  for (int off = 32; off; off >>= 1){ s += __shfl_down(s, off); q += __shfl_down(q, off); }
  __shared__ float ls[4], lq[4];
  int wid = t >> 6, lane = t & 63;
  if (lane == 0){ ls[wid] = s; lq[wid] = q; }
  __syncthreads();
  if (t == 0){
    float S2 = ls[0]+ls[1]+ls[2]+ls[3], Q = lq[0]+lq[1]+lq[2]+lq[3];
    float mu = S2 * (1.0f/(float)ROWSTR);
    float var = Q * (1.0f/(float)ROWSTR) - mu*mu;
    mr[r] = make_float2(mu, rsqrtf(var + 1e-6f));
  }
}

// ---- gates GEMM: [x | LN(csum)] (64x256) @ w_hid_t -> f,u packed bf16x2 ----
__launch_bounds__(256, 1)
__global__ void k_gates(const float* __restrict__ x, const unsigned short* __restrict__ csum,
                        const float2* __restrict__ mr, const float* __restrict__ ln_g,
                        const float* __restrict__ ln_b, const unsigned short* __restrict__ wht,
                        const float* __restrict__ b_hid, unsigned int* __restrict__ fu){
  __shared__ unsigned short lA[64*72];
  __shared__ unsigned short lB[NGATE*72];
  const int h = blockIdx.y;
  const int m0 = blockIdx.x * 64;
  const int tid = threadIdx.x;
  const int lane = tid & 63, wid = tid >> 6;
  const int wm = wid >> 1, wn = wid & 1;      // 2x2 wave grid: 32 rows x 192 cols each
  f32x4 acc[2][12];
  #pragma unroll
  for (int i = 0; i < 2; ++i)
    #pragma unroll
    for (int j = 0; j < 12; ++j) acc[i][j] = (f32x4){0.f,0.f,0.f,0.f};

  const int arow = tid >> 2;                  // 0..63
  const int akg  = (tid & 3) * 16;            // 0,16,32,48
  const int r_g  = m0 + arow;

  for (int kk = 0; kk < 4; ++kk){
    __syncthreads();
    { // stage A (64 x 64 bf16)
      u16x8 t0, t1;
      if (kk < 2){
        const float4* px = (const float4*)(x + (size_t)r_g*ROWSTR + h*Aa + kk*64 + akg);
        float4 v0 = px[0], v1 = px[1], v2 = px[2], v3 = px[3];
        t0[0]=f2bf(v0.x); t0[1]=f2bf(v0.y); t0[2]=f2bf(v0.z); t0[3]=f2bf(v0.w);
        t0[4]=f2bf(v1.x); t0[5]=f2bf(v1.y); t0[6]=f2bf(v1.z); t0[7]=f2bf(v1.w);
        t1[0]=f2bf(v2.x); t1[1]=f2bf(v2.y); t1[2]=f2bf(v2.z); t1[3]=f2bf(v2.w);
        t1[4]=f2bf(v3.x); t1[5]=f2bf(v3.y); t1[6]=f2bf(v3.z); t1[7]=f2bf(v3.w);
      } else {
        int a0 = (kk-2)*64 + akg;
        const u16x8* pc = (const u16x8*)(csum + (size_t)r_g*ROWSTR + h*Aa + a0);
        u16x8 c0 = pc[0], c1 = pc[1];
        float2 m = mr[r_g];
        const float* pg = ln_g + h*Aa + a0;
        const float* pb = ln_b + h*Aa + a0;
        #pragma unroll
        for (int i = 0; i < 8; ++i){
          t0[i] = f2bf((bf2f(c0[i]) - m.x)*m.y*pg[i]   + pb[i]);
          t1[i] = f2bf((bf2f(c1[i]) - m.x)*m.y*pg[8+i] + pb[8+i]);
        }
      }
      u16x8* dst = (u16x8*)&lA[arow*72 + akg];
      dst[0] = t0; dst[1] = t1;
    }
    // stage B (64 x 384 bf16, stored [n][k] from pre-transposed wht)
    #pragma unroll
    for (int i = 0; i < 12; ++i){
      int chunk = tid + i*256;                 // 0..3071
      int n = chunk >> 3, kg = (chunk & 7)*8;
      *(u16x8*)&lB[n*72 + kg] =
        *(const u16x8*)(wht + ((size_t)h*NGATE + n)*KDIM + kk*64 + kg);
    }
    __syncthreads();
    #pragma unroll
    for (int ks = 0; ks < 2; ++ks){
      int kb = ks*32 + (lane >> 4)*8;
      bf16x8 a0 = __builtin_bit_cast(bf16x8, *(const u16x8*)&lA[(wm*32 +      (lane&15))*72 + kb]);
      bf16x8 a1 = __builtin_bit_cast(bf16x8, *(const u16x8*)&lA[(wm*32 + 16 + (lane&15))*72 + kb]);
      #pragma unroll
      for (int j = 0; j < 12; ++j){
        bf16x8 bv = __builtin_bit_cast(bf16x8, *(const u16x8*)&lB[(wn*192 + j*16 + (lane&15))*72 + kb]);
        acc[0][j] = __builtin_amdgcn_mfma_f32_16x16x32_bf16(a0, bv, acc[0][j], 0, 0, 0);
        acc[1][j] = __builtin_amdgcn_mfma_f32_16x16x32_bf16(a1, bv, acc[1][j], 0, 0, 0);
      }
    }
  }
  // epilogue: sigmoid/relu pointwise, pack (u,f) as 2xbf16
  const int ln15 = lane & 15, lq = lane >> 4;
  #pragma unroll
  for (int mf = 0; mf < 2; ++mf){
    int rowb = m0 + wm*32 + mf*16 + lq*4;
    #pragma unroll
    for (int tb = 0; tb < 4; ++tb){
      int d = (wn*4 + tb)*16 + ln15;
      float big = b_hid[h*NGATE + d];
      float bfg = b_hid[h*NGATE + 128 + d];
      float bhd = b_hid[h*NGATE + 256 + d];
      f32x4 aig = acc[mf][tb*3+0];
      f32x4 afg = acc[mf][tb*3+1];
      f32x4 ahd = acc[mf][tb*3+2];
      #pragma unroll
      for (int r = 0; r < 4; ++r){
        float fg = sigf(afg[r] + bfg);
        float uu = sigf(aig[r] + big) * fmaxf(ahd[r] + bhd, 0.0f);
        fu[(size_t)(rowb + r)*ROWSTR + h*Dd + d] =
          ((unsigned int)f2bf(uu) << 16) | (unsigned int)f2bf(fg);
      }
    }
  }
}

// ---- recurrence pass A: per-chunk (F, C) summaries ----
__global__ void k_recur_a(const unsigned int* __restrict__ fu,
                          float* __restrict__ Fc, float* __restrict__ Cc){
  int c = blockIdx.x;
  int k = c % NCH; int hb = c / NCH;
  int b = hb / Hh, h = hb % Hh;
  int d = threadIdx.x;
  const unsigned int* p = fu + ((size_t)(b*Ss + k*CLEN)*Hh + h)*Dd + d;
  float F = 1.f, C = 0.f;
  #pragma unroll 4
  for (int i = 0; i < CLEN; ++i){
    unsigned int v = p[(size_t)i*ROWSTR];
    float f = bf2f((unsigned short)v);
    float u = bf2f((unsigned short)(v >> 16));
    C = fmaf(f, C, u);
    F *= f;
  }
  Fc[(size_t)c*Dd + d] = F;
  Cc[(size_t)c*Dd + d] = C;
}

// ---- recurrence pass C: carry-in + write cell (fp32) into d_out ----
__global__ void k_recur_c(const unsigned int* __restrict__ fu, const float* __restrict__ Fc,
                          const float* __restrict__ Cc, const float* __restrict__ init_cx,
                          float* __restrict__ out){
  int c = blockIdx.x;
  int k = c % NCH; int hb = c / NCH;
  int b = hb / Hh, h = hb % Hh;
  int d = threadIdx.x;
  float carry = init_cx[h*Dd + d];
  const float* fp = Fc + (size_t)hb*NCH*Dd + d;
  const float* cp = Cc + (size_t)hb*NCH*Dd + d;
  for (int j = 0; j < k; ++j) carry = fmaf(fp[(size_t)j*Dd], carry, cp[(size_t)j*Dd]);
  const unsigned int* p = fu + ((size_t)(b*Ss + k*CLEN)*Hh + h)*Dd + d;
  float* q = out + ((size_t)(b*Ss + k*CLEN)*Hh + h)*Dd + d;
  #pragma unroll 2
  for (int i = 0; i < CLEN; ++i){
    unsigned int v = p[(size_t)i*ROWSTR];
    float f = bf2f((unsigned short)v);
    float u = bf2f((unsigned short)(v >> 16));
    carry = fmaf(f, carry, u);
    q[(size_t)i*ROWSTR] = carry;
  }
}

// ---- og GEMM: [x | cell] @ w_og_t -> sigmoid -> out = og*cell (in-place over cell) ----
__launch_bounds__(256, 1)
__global__ void k_og(const float* __restrict__ x, const unsigned short* __restrict__ wot,
                     const float* __restrict__ b_og, float* __restrict__ out){
  __shared__ unsigned short lA[64*72];
  __shared__ unsigned short lB[Dd*72];
  const int h = blockIdx.y;
  const int m0 = blockIdx.x * 64;
  const int tid = threadIdx.x;
  const int lane = tid & 63, wid = tid >> 6;
  const int wm = wid >> 1, wn = wid & 1;      // 2x2: 32 rows x 64 cols per wave
  f32x4 acc[2][4];
  #pragma unroll
  for (int i = 0; i < 2; ++i)
    #pragma unroll
    for (int j = 0; j < 4; ++j) acc[i][j] = (f32x4){0.f,0.f,0.f,0.f};

  const int arow = tid >> 2;
  const int akg  = (tid & 3) * 16;
  const int r_g  = m0 + arow;

  for (int kk = 0; kk < 4; ++kk){
    __syncthreads();
    { // stage A: k<128 from x, k>=128 from cell (resident in out)
      const float* src = (kk < 2)
        ? (x   + (size_t)r_g*ROWSTR + h*Aa + kk*64 + akg)
        : (out + (size_t)r_g*ROWSTR + h*Dd + (kk-2)*64 + akg);
      const float4* p4 = (const float4*)src;
      float4 v0 = p4[0], v1 = p4[1], v2 = p4[2], v3 = p4[3];
      u16x8 t0, t1;
      t0[0]=f2bf(v0.x); t0[1]=f2bf(v0.y); t0[2]=f2bf(v0.z); t0[3]=f2bf(v0.w);
      t0[4]=f2bf(v1.x); t0[5]=f2bf(v1.y); t0[6]=f2bf(v1.z); t0[7]=f2bf(v1.w);
      t1[0]=f2bf(v2.x); t1[1]=f2bf(v2.y); t1[2]=f2bf(v2.z); t1[3]=f2bf(v2.w);
      t1[4]=f2bf(v3.x); t1[5]=f2bf(v3.y); t1[6]=f2bf(v3.z); t1[7]=f2bf(v3.w);
      u16x8* dst = (u16x8*)&lA[arow*72 + akg];
      dst[0] = t0; dst[1] = t1;
    }
    #pragma unroll
    for (int i = 0; i < 4; ++i){
      int chunk = tid + i*256;                 // 0..1023
      int n = chunk >> 3, kg = (chunk & 7)*8;
      *(u16x8*)&lB[n*72 + kg] =
        *(const u16x8*)(wot + ((size_t)h*Dd + n)*KDIM + kk*64 + kg);
    }
    __syncthreads();
    #pragma unroll
    for (int ks = 0; ks < 2; ++ks){
      int kb = ks*32 + (lane >> 4)*8;
      bf16x8 a0 = __builtin_bit_cast(bf16x8, *(const u16x8*)&lA[(wm*32 +      (lane&15))*72 + kb]);
      bf16x8 a1 = __builtin_bit_cast(bf16x8, *(const u16x8*)&lA[(wm*32 + 16 + (lane&15))*72 + kb]);
      #pragma unroll
      for (int j = 0; j < 4; ++j){
        bf16x8 bv = __builtin_bit_cast(bf16x8, *(const u16x8*)&lB[(wn*64 + j*16 + (lane&15))*72 + kb]);
        acc[0][j] = __builtin_amdgcn_mfma_f32_16x16x32_bf16(a0, bv, acc[0][j], 0, 0, 0);
        acc[1][j] = __builtin_amdgcn_mfma_f32_16x16x32_bf16(a1, bv, acc[1][j], 0, 0, 0);
      }
    }
  }
  const int ln15 = lane & 15, lq = lane >> 4;
  #pragma unroll
  for (int mf = 0; mf < 2; ++mf){
    int rowb = m0 + wm*32 + mf*16 + lq*4;
    #pragma unroll
    for (int j = 0; j < 4; ++j){
      int d = wn*64 + j*16 + ln15;
      float bo = b_og[h*Dd + d];
      #pragma unroll
      for (int r = 0; r < 4; ++r){
        size_t oi = (size_t)(rowb + r)*ROWSTR + h*Dd + d;
        float cell = out[oi];
        out[oi] = sigf(acc[mf][j][r] + bo) * cell;
      }
    }
  }
}

extern "C" void kernel_launch(void* const* d_in, const int* in_sizes, int n_in,
                              void* d_out, int out_size, void* d_ws, size_t ws_size,
                              hipStream_t stream){
  const float* x       = (const float*)d_in[0];
  const float* w_hid   = (const float*)d_in[1];
  const float* b_hid   = (const float*)d_in[2];
  const float* w_og    = (const float*)d_in[3];
  const float* b_og    = (const float*)d_in[4];
  const float* ln_g    = (const float*)d_in[5];
  const float* ln_b    = (const float*)d_in[6];
  const float* init_cx = (const float*)d_in[7];
  float* out = (float*)d_out;

  char* ws = (char*)d_ws;
  unsigned short* csum = (unsigned short*)(ws);                      // 64 MiB
  unsigned int*   fu   = (unsigned int*)  (ws + ((size_t)64  << 20)); // 128 MiB
  float*          tot  = (float*)         (ws + ((size_t)192 << 20)); // 1 MiB
  float*          Fc   = (float*)         (ws + ((size_t)193 << 20)); // 1 MiB
  float*          Cc   = (float*)         (ws + ((size_t)194 << 20)); // 1 MiB
  float2*         mr   = (float2*)        (ws + ((size_t)195 << 20)); // 128 KiB
  unsigned short* wht  = (unsigned short*)(ws + ((size_t)196 << 20)); // 3 MiB
  unsigned short* wot  = (unsigned short*)(ws + ((size_t)199 << 20)); // 1 MiB

  k_conv_whid<<<2048, 256, 0, stream>>>(w_hid, wht);
  k_conv_wog <<<1024, 256, 0, stream>>>(w_og,  wot);
  k_cumsum_a <<<Bb*Hh*NCH, Aa, 0, stream>>>(x, tot);
  k_cumsum_c <<<Bb*Hh*NCH, Aa, 0, stream>>>(x, tot, csum);
  k_stats    <<<ROWS, 256, 0, stream>>>(csum, mr);
  k_gates    <<<dim3(ROWS/64, Hh), 256, 0, stream>>>(x, csum, mr, ln_g, ln_b, wht, b_hid, fu);
  k_recur_a  <<<Bb*Hh*NCH, Dd, 0, stream>>>(fu, Fc, Cc);
  k_recur_c  <<<Bb*Hh*NCH, Dd, 0, stream>>>(fu, Fc, Cc, init_cx, out);
  k_og       <<<dim3(ROWS/64, Hh), 256, 0, stream>>>(x, wot, b_og, out);
}